// Round 1
// baseline (555.212 us; speedup 1.0000x reference)
//
#include <hip/hip_runtime.h>

// MoE MLP: B=2,S=2048,H=1024,I=2048,E=8,TOPK=2  -> T=4096 tokens, 8192 entries.
// Sparse grouped-GEMM: route -> cast fp32->bf16 -> gemm1(gate+up+silu fused) -> gemm2(+scatter).

#define H_DIM 1024
#define I_DIM 2048
#define N_EXP 8
#define N_TOK 4096
#define N_ENT 8192
#define CAP   9216   // 8192 + 8*128 padding capacity

typedef __attribute__((ext_vector_type(8))) short bhalf8;
typedef __attribute__((ext_vector_type(4))) float floatx4;

__device__ __forceinline__ unsigned short f2bf(float f) {
  unsigned int u = __float_as_uint(f);
  u += 0x7fffu + ((u >> 16) & 1u);   // round-to-nearest-even
  return (unsigned short)(u >> 16);
}

__device__ __forceinline__ void ld16(const void* g, void* l) {
  // async global->LDS, 16B per lane; LDS dst = wave-uniform base + lane*16
  __builtin_amdgcn_global_load_lds(
      (const __attribute__((address_space(1))) unsigned int*)g,
      (__attribute__((address_space(3))) unsigned int*)l, 16, 0, 0);
}

// ---------------- routing: bucket (token,slot) entries by expert ----------------
__global__ __launch_bounds__(256) void route_kernel(
    const int* __restrict__ idx, const float* __restrict__ wts,
    int* __restrict__ perm, float* __restrict__ pw,
    int* __restrict__ counts, int* __restrict__ poff)
{
  __shared__ int cnt[N_EXP], cur[N_EXP], off[N_EXP];
  const int t = threadIdx.x;
  if (t < N_EXP) { cnt[t] = 0; cur[t] = 0; }
  __syncthreads();
  for (int i = t; i < N_ENT; i += 256) atomicAdd(&cnt[idx[i] & 7], 1);
  __syncthreads();
  if (t == 0) {
    int o = 0;
    for (int e = 0; e < N_EXP; e++) {
      off[e] = o; counts[e] = cnt[e]; poff[e] = o;
      o += ((cnt[e] + 127) >> 7) << 7;   // pad each segment to 128 rows
    }
  }
  __syncthreads();
  for (int i = t; i < N_ENT; i += 256) {
    int e = idx[i] & 7;
    int p = atomicAdd(&cur[e], 1);
    perm[off[e] + p] = i >> 1;   // token = entry / TOPK
    pw[off[e] + p] = wts[i];
  }
}

// ---------------- fp32 -> bf16 cast ----------------
__global__ __launch_bounds__(256) void cast_kernel(
    const float* __restrict__ s, unsigned short* __restrict__ d, int n)
{
  int i = (blockIdx.x * 256 + threadIdx.x) * 8;
  if (i >= n) return;
  const float4* sp = (const float4*)(s + i);
  float4 a = sp[0], b = sp[1];
  bhalf8 o;
  o[0] = (short)f2bf(a.x); o[1] = (short)f2bf(a.y); o[2] = (short)f2bf(a.z); o[3] = (short)f2bf(a.w);
  o[4] = (short)f2bf(b.x); o[5] = (short)f2bf(b.y); o[6] = (short)f2bf(b.z); o[7] = (short)f2bf(b.w);
  *(bhalf8*)(d + i) = o;
}

// ---------------- GEMM1: act = silu(X Wg^T) * (X Wu^T), gathered rows ----------------
// block tile: 128(M) x 64(N per matrix), BK=32. 4 waves as 2x2; wave tile 64x32 (x2 matrices).
// LDS layout K-chunked: cell = kq*ROWS + r, 16B per cell -> conflict-free b128 reads
// and exactly matches global_load_lds lane->(base+lane*16) mapping.
__global__ __launch_bounds__(256, 2) void gemm1_kernel(
    const unsigned short* __restrict__ xb,
    const unsigned short* __restrict__ gbw,
    const unsigned short* __restrict__ ubw,
    const int* __restrict__ perm,
    const int* __restrict__ counts,
    const int* __restrict__ poff,
    unsigned short* __restrict__ act)
{
  const int e = blockIdx.z;
  const int Ne = counts[e];
  const int mt = blockIdx.y;
  if (mt * 128 >= Ne) return;
  const int base = poff[e];
  const int n0 = blockIdx.x * 64;

  __shared__ __align__(16) unsigned short As[128 * 32];
  __shared__ __align__(16) unsigned short Bgs[64 * 32];
  __shared__ __align__(16) unsigned short Bus[64 * 32];

  const int tid = threadIdx.x;
  const int lane = tid & 63;
  const int w = tid >> 6;
  const int wm = w >> 1, wn = w & 1;

  // A staging: 512 cells (kq in [0,4), m in [0,128)); wave w covers [w*128, w*128+128)
  const int cA0 = w * 128 + lane, cA1 = cA0 + 64;
  const int mA0 = cA0 & 127, kqA0 = cA0 >> 7;
  const int mA1 = cA1 & 127, kqA1 = cA1 >> 7;
  int rr0 = mt * 128 + mA0; rr0 = rr0 < Ne ? rr0 : Ne - 1;   // clamp padded rows
  int rr1 = mt * 128 + mA1; rr1 = rr1 < Ne ? rr1 : Ne - 1;
  const int tok0 = perm[base + rr0];
  const int tok1 = perm[base + rr1];
  const unsigned short* ga0 = xb + (size_t)tok0 * H_DIM + kqA0 * 8;
  const unsigned short* ga1 = xb + (size_t)tok1 * H_DIM + kqA1 * 8;
  unsigned short* lA0 = &As[(w * 128) * 8];
  unsigned short* lA1 = &As[(w * 128 + 64) * 8];

  // B staging: 256 cells each (kq in [0,4), n in [0,64)); wave w covers [w*64, w*64+64)
  const int cB = w * 64 + lane;
  const int nB = cB & 63, kqB = cB >> 6;
  const size_t wbase = (size_t)e * I_DIM * H_DIM + (size_t)(n0 + nB) * H_DIM + kqB * 8;
  const unsigned short* gg = gbw + wbase;
  const unsigned short* gu = ubw + wbase;
  unsigned short* lBg = &Bgs[(w * 64) * 8];
  unsigned short* lBu = &Bus[(w * 64) * 8];

  floatx4 zero = {0.f, 0.f, 0.f, 0.f};
  floatx4 accg[4][2], accu[4][2];
#pragma unroll
  for (int i = 0; i < 4; i++)
#pragma unroll
    for (int j = 0; j < 2; j++) { accg[i][j] = zero; accu[i][j] = zero; }

  const int quad = lane >> 4, lm = lane & 15;

  for (int k0 = 0; k0 < H_DIM; k0 += 32) {
    __syncthreads();
    ld16(ga0 + k0, lA0);
    ld16(ga1 + k0, lA1);
    ld16(gg + k0, lBg);
    ld16(gu + k0, lBu);
    __syncthreads();   // includes vmcnt(0) drain of the async LDS loads
    bhalf8 a[4], bg[2], bu[2];
#pragma unroll
    for (int i = 0; i < 4; i++)
      a[i] = *(const bhalf8*)&As[(quad * 128 + wm * 64 + i * 16 + lm) * 8];
#pragma unroll
    for (int j = 0; j < 2; j++) {
      bg[j] = *(const bhalf8*)&Bgs[(quad * 64 + wn * 32 + j * 16 + lm) * 8];
      bu[j] = *(const bhalf8*)&Bus[(quad * 64 + wn * 32 + j * 16 + lm) * 8];
    }
#pragma unroll
    for (int i = 0; i < 4; i++)
#pragma unroll
      for (int j = 0; j < 2; j++) {
        accg[i][j] = __builtin_amdgcn_mfma_f32_16x16x32_bf16(a[i], bg[j], accg[i][j], 0, 0, 0);
        accu[i][j] = __builtin_amdgcn_mfma_f32_16x16x32_bf16(a[i], bu[j], accu[i][j], 0, 0, 0);
      }
  }

  // epilogue: h = silu(g)*u -> bf16 into sorted act buffer (padding rows written too; harmless)
#pragma unroll
  for (int i = 0; i < 4; i++) {
#pragma unroll
    for (int r = 0; r < 4; r++) {
      int row = mt * 128 + wm * 64 + i * 16 + quad * 4 + r;
      size_t rowoff = (size_t)(base + row) * I_DIM;
#pragma unroll
      for (int j = 0; j < 2; j++) {
        int col = n0 + wn * 32 + j * 16 + lm;
        float g = accg[i][j][r];
        float u = accu[i][j][r];
        float h = (g / (1.f + __expf(-g))) * u;
        act[rowoff + col] = (unsigned short)f2bf(h);
      }
    }
  }
}

// ---------------- GEMM2: out[tok] += w * (act x down^T) ----------------
// block tile 128x128, BK=32, 4 waves 2x2, wave tile 64x64 (acc 4x4).
__global__ __launch_bounds__(256, 2) void gemm2_kernel(
    const unsigned short* __restrict__ act,
    const unsigned short* __restrict__ dbw,
    const int* __restrict__ perm,
    const float* __restrict__ pw,
    const int* __restrict__ counts,
    const int* __restrict__ poff,
    float* __restrict__ out)
{
  const int e = blockIdx.z;
  const int Ne = counts[e];
  const int mt = blockIdx.y;
  if (mt * 128 >= Ne) return;
  const int base = poff[e];
  const int n0 = blockIdx.x * 128;

  __shared__ __align__(16) unsigned short As[128 * 32];
  __shared__ __align__(16) unsigned short Bs[128 * 32];

  const int tid = threadIdx.x;
  const int lane = tid & 63;
  const int w = tid >> 6;
  const int wm = w >> 1, wn = w & 1;

  const int cA0 = w * 128 + lane, cA1 = cA0 + 64;
  const int mA0 = cA0 & 127, kqA0 = cA0 >> 7;
  const int mA1 = cA1 & 127, kqA1 = cA1 >> 7;
  const unsigned short* ga0 = act + (size_t)(base + mt * 128 + mA0) * I_DIM + kqA0 * 8;
  const unsigned short* ga1 = act + (size_t)(base + mt * 128 + mA1) * I_DIM + kqA1 * 8;
  unsigned short* lA0 = &As[(w * 128) * 8];
  unsigned short* lA1 = &As[(w * 128 + 64) * 8];

  const int cB0 = w * 128 + lane, cB1 = cB0 + 64;
  const int nB0 = cB0 & 127, kqB0 = cB0 >> 7;
  const int nB1 = cB1 & 127, kqB1 = cB1 >> 7;
  const unsigned short* gb0 = dbw + (size_t)e * H_DIM * I_DIM + (size_t)(n0 + nB0) * I_DIM + kqB0 * 8;
  const unsigned short* gb1 = dbw + (size_t)e * H_DIM * I_DIM + (size_t)(n0 + nB1) * I_DIM + kqB1 * 8;
  unsigned short* lB0 = &Bs[(w * 128) * 8];
  unsigned short* lB1 = &Bs[(w * 128 + 64) * 8];

  floatx4 zero = {0.f, 0.f, 0.f, 0.f};
  floatx4 acc[4][4];
#pragma unroll
  for (int i = 0; i < 4; i++)
#pragma unroll
    for (int j = 0; j < 4; j++) acc[i][j] = zero;

  const int quad = lane >> 4, lm = lane & 15;

  for (int k0 = 0; k0 < I_DIM; k0 += 32) {
    __syncthreads();
    ld16(ga0 + k0, lA0);
    ld16(ga1 + k0, lA1);
    ld16(gb0 + k0, lB0);
    ld16(gb1 + k0, lB1);
    __syncthreads();
    bhalf8 a[4], b[4];
#pragma unroll
    for (int i = 0; i < 4; i++)
      a[i] = *(const bhalf8*)&As[(quad * 128 + wm * 64 + i * 16 + lm) * 8];
#pragma unroll
    for (int j = 0; j < 4; j++)
      b[j] = *(const bhalf8*)&Bs[(quad * 128 + wn * 64 + j * 16 + lm) * 8];
#pragma unroll
    for (int i = 0; i < 4; i++)
#pragma unroll
      for (int j = 0; j < 4; j++)
        acc[i][j] = __builtin_amdgcn_mfma_f32_16x16x32_bf16(a[i], b[j], acc[i][j], 0, 0, 0);
  }

  // scatter epilogue: out[tok] += w * val  (each token has exactly 2 entries device-wide)
#pragma unroll
  for (int i = 0; i < 4; i++) {
#pragma unroll
    for (int r = 0; r < 4; r++) {
      int row = mt * 128 + wm * 64 + i * 16 + quad * 4 + r;
      if (row < Ne) {
        int tok = perm[base + row];
        float wt = pw[base + row];
        float* orow = out + (size_t)tok * H_DIM;
#pragma unroll
        for (int j = 0; j < 4; j++) {
          int col = n0 + wn * 64 + j * 16 + lm;
          atomicAdd(orow + col, wt * acc[i][j][r]);
        }
      }
    }
  }
}

extern "C" void kernel_launch(void* const* d_in, const int* in_sizes, int n_in,
                              void* d_out, int out_size, void* d_ws, size_t ws_size,
                              hipStream_t stream) {
  const float* x    = (const float*)d_in[0];
  const int*   idx  = (const int*)d_in[1];
  const float* wts  = (const float*)d_in[2];
  const float* gate = (const float*)d_in[3];
  const float* up   = (const float*)d_in[4];
  const float* down = (const float*)d_in[5];
  float* out = (float*)d_out;
  char* ws = (char*)d_ws;

  // workspace layout (bytes)
  unsigned short* xb  = (unsigned short*)(ws + 0);            //  8,388,608
  unsigned short* gbw = (unsigned short*)(ws + 8388608);      // 33,554,432
  unsigned short* ubw = (unsigned short*)(ws + 41943040);     // 33,554,432
  unsigned short* dbw = (unsigned short*)(ws + 75497472);     // 33,554,432
  unsigned short* act = (unsigned short*)(ws + 109051904);    // 37,748,736 (9216*2048*2)
  int*   perm   = (int*)(ws + 146800640);                     // 36,864
  float* pw     = (float*)(ws + 146837504);                   // 36,864
  int*   counts = (int*)(ws + 146874368);                     // 32
  int*   poff   = (int*)(ws + 146874432);                     // 32

  hipMemsetAsync(out, 0, (size_t)N_TOK * H_DIM * sizeof(float), stream);

  route_kernel<<<1, 256, 0, stream>>>(idx, wts, perm, pw, counts, poff);

  cast_kernel<<<(N_TOK * H_DIM) / (256 * 8), 256, 0, stream>>>(x, xb, N_TOK * H_DIM);
  cast_kernel<<<(N_EXP * I_DIM * H_DIM) / (256 * 8), 256, 0, stream>>>(gate, gbw, N_EXP * I_DIM * H_DIM);
  cast_kernel<<<(N_EXP * I_DIM * H_DIM) / (256 * 8), 256, 0, stream>>>(up, ubw, N_EXP * I_DIM * H_DIM);
  cast_kernel<<<(N_EXP * H_DIM * I_DIM) / (256 * 8), 256, 0, stream>>>(down, dbw, N_EXP * H_DIM * I_DIM);

  gemm1_kernel<<<dim3(I_DIM / 64, 64, N_EXP), 256, 0, stream>>>(
      xb, gbw, ubw, perm, counts, poff, act);

  gemm2_kernel<<<dim3(H_DIM / 128, 64, N_EXP), 256, 0, stream>>>(
      act, dbw, perm, pw, counts, poff, out);
}

// Round 2
// 552.820 us; speedup vs baseline: 1.0043x; 1.0043x over previous
//
#include <hip/hip_runtime.h>

// MoE MLP: B=2,S=2048,H=1024,I=2048,E=8,TOPK=2  -> T=4096 tokens, 8192 entries.
// route -> cast fp32->bf16 -> gemm1(gate+up+silu fused) -> gemm2(weighted rows) -> combine.

#define H_DIM 1024
#define I_DIM 2048
#define N_EXP 8
#define N_TOK 4096
#define N_ENT 8192
#define CAP   9216   // 8192 + 8*128 padding capacity

typedef __attribute__((ext_vector_type(8))) short bhalf8;
typedef __attribute__((ext_vector_type(4))) float floatx4;

__device__ __forceinline__ unsigned short f2bf(float f) {
  unsigned int u = __float_as_uint(f);
  u += 0x7fffu + ((u >> 16) & 1u);   // round-to-nearest-even
  return (unsigned short)(u >> 16);
}

__device__ __forceinline__ void ld16(const void* g, void* l) {
  // async global->LDS, 16B per lane; LDS dst = wave-uniform base + lane*16
  __builtin_amdgcn_global_load_lds(
      (const __attribute__((address_space(1))) unsigned int*)g,
      (__attribute__((address_space(3))) unsigned int*)l, 16, 0, 0);
}

// ---------------- routing: bucket (token,slot) entries by expert ----------------
__global__ __launch_bounds__(256) void route_kernel(
    const int* __restrict__ idx, const float* __restrict__ wts,
    int* __restrict__ perm, float* __restrict__ pw, int* __restrict__ inv,
    int* __restrict__ counts, int* __restrict__ poff)
{
  __shared__ int cnt[N_EXP], cur[N_EXP], off[N_EXP];
  const int t = threadIdx.x;
  if (t < N_EXP) { cnt[t] = 0; cur[t] = 0; }
  __syncthreads();
  for (int i = t; i < N_ENT; i += 256) atomicAdd(&cnt[idx[i] & 7], 1);
  __syncthreads();
  if (t == 0) {
    int o = 0;
    for (int e = 0; e < N_EXP; e++) {
      off[e] = o; counts[e] = cnt[e]; poff[e] = o;
      o += ((cnt[e] + 127) >> 7) << 7;   // pad each segment to 128 rows
    }
  }
  __syncthreads();
  for (int i = t; i < N_ENT; i += 256) {
    int e = idx[i] & 7;
    int p = atomicAdd(&cur[e], 1);
    int pos = off[e] + p;
    perm[pos] = i >> 1;   // token = entry / TOPK
    pw[pos] = wts[i];
    inv[i] = pos;         // entry (token,slot) -> permuted position
  }
}

// ---------------- fp32 -> bf16 cast ----------------
__global__ __launch_bounds__(256) void cast_kernel(
    const float* __restrict__ s, unsigned short* __restrict__ d, int n)
{
  int i = (blockIdx.x * 256 + threadIdx.x) * 8;
  if (i >= n) return;
  const float4* sp = (const float4*)(s + i);
  float4 a = sp[0], b = sp[1];
  bhalf8 o;
  o[0] = (short)f2bf(a.x); o[1] = (short)f2bf(a.y); o[2] = (short)f2bf(a.z); o[3] = (short)f2bf(a.w);
  o[4] = (short)f2bf(b.x); o[5] = (short)f2bf(b.y); o[6] = (short)f2bf(b.z); o[7] = (short)f2bf(b.w);
  *(bhalf8*)(d + i) = o;
}

// ---------------- GEMM1: act = silu(X Wg^T) * (X Wu^T), gathered rows ----------------
// block tile: 128(M) x 64(N per matrix), BK=32. 4 waves as 2x2; wave tile 64x32 (x2 matrices).
// LDS K-chunked: cell = kq*ROWS + r, 16B/cell -> conflict-free b128 reads, matches ld16 mapping.
__global__ __launch_bounds__(256, 3) void gemm1_kernel(
    const unsigned short* __restrict__ xb,
    const unsigned short* __restrict__ gbw,
    const unsigned short* __restrict__ ubw,
    const int* __restrict__ perm,
    const int* __restrict__ counts,
    const int* __restrict__ poff,
    unsigned short* __restrict__ act)
{
  const int e = blockIdx.z;
  const int Ne = counts[e];
  const int mt = blockIdx.y;
  if (mt * 128 >= Ne) return;
  const int base = poff[e];
  const int n0 = blockIdx.x * 64;

  __shared__ __align__(16) unsigned short As[128 * 32];
  __shared__ __align__(16) unsigned short Bgs[64 * 32];
  __shared__ __align__(16) unsigned short Bus[64 * 32];

  const int tid = threadIdx.x;
  const int lane = tid & 63;
  const int w = tid >> 6;
  const int wm = w >> 1, wn = w & 1;

  // A staging: 512 cells (kq in [0,4), m in [0,128)); wave w covers [w*128, w*128+128)
  const int cA0 = w * 128 + lane, cA1 = cA0 + 64;
  const int mA0 = cA0 & 127, kqA0 = cA0 >> 7;
  const int mA1 = cA1 & 127, kqA1 = cA1 >> 7;
  int rr0 = mt * 128 + mA0; rr0 = rr0 < Ne ? rr0 : Ne - 1;   // clamp padded rows
  int rr1 = mt * 128 + mA1; rr1 = rr1 < Ne ? rr1 : Ne - 1;
  const int tok0 = perm[base + rr0];
  const int tok1 = perm[base + rr1];
  const unsigned short* ga0 = xb + (size_t)tok0 * H_DIM + kqA0 * 8;
  const unsigned short* ga1 = xb + (size_t)tok1 * H_DIM + kqA1 * 8;
  unsigned short* lA0 = &As[(w * 128) * 8];
  unsigned short* lA1 = &As[(w * 128 + 64) * 8];

  // B staging: 256 cells each (kq in [0,4), n in [0,64)); wave w covers [w*64, w*64+64)
  const int cB = w * 64 + lane;
  const int nB = cB & 63, kqB = cB >> 6;
  const size_t wbase = (size_t)e * I_DIM * H_DIM + (size_t)(n0 + nB) * H_DIM + kqB * 8;
  const unsigned short* gg = gbw + wbase;
  const unsigned short* gu = ubw + wbase;
  unsigned short* lBg = &Bgs[(w * 64) * 8];
  unsigned short* lBu = &Bus[(w * 64) * 8];

  floatx4 zero = {0.f, 0.f, 0.f, 0.f};
  floatx4 accg[4][2], accu[4][2];
#pragma unroll
  for (int i = 0; i < 4; i++)
#pragma unroll
    for (int j = 0; j < 2; j++) { accg[i][j] = zero; accu[i][j] = zero; }

  const int quad = lane >> 4, lm = lane & 15;

  for (int k0 = 0; k0 < H_DIM; k0 += 32) {
    __syncthreads();
    ld16(ga0 + k0, lA0);
    ld16(ga1 + k0, lA1);
    ld16(gg + k0, lBg);
    ld16(gu + k0, lBu);
    __syncthreads();   // includes vmcnt(0) drain of the async LDS loads
    bhalf8 a[4], bg[2], bu[2];
#pragma unroll
    for (int i = 0; i < 4; i++)
      a[i] = *(const bhalf8*)&As[(quad * 128 + wm * 64 + i * 16 + lm) * 8];
#pragma unroll
    for (int j = 0; j < 2; j++) {
      bg[j] = *(const bhalf8*)&Bgs[(quad * 64 + wn * 32 + j * 16 + lm) * 8];
      bu[j] = *(const bhalf8*)&Bus[(quad * 64 + wn * 32 + j * 16 + lm) * 8];
    }
#pragma unroll
    for (int i = 0; i < 4; i++)
#pragma unroll
      for (int j = 0; j < 2; j++) {
        accg[i][j] = __builtin_amdgcn_mfma_f32_16x16x32_bf16(a[i], bg[j], accg[i][j], 0, 0, 0);
        accu[i][j] = __builtin_amdgcn_mfma_f32_16x16x32_bf16(a[i], bu[j], accu[i][j], 0, 0, 0);
      }
  }

  // epilogue: h = silu(g)*u -> bf16 into sorted act buffer (padding rows written too; harmless)
#pragma unroll
  for (int i = 0; i < 4; i++) {
#pragma unroll
    for (int r = 0; r < 4; r++) {
      int row = mt * 128 + wm * 64 + i * 16 + quad * 4 + r;
      size_t rowoff = (size_t)(base + row) * I_DIM;
#pragma unroll
      for (int j = 0; j < 2; j++) {
        int col = n0 + wn * 32 + j * 16 + lm;
        float g = accg[i][j][r];
        float u = accu[i][j][r];
        float h = (g / (1.f + __expf(-g))) * u;
        act[rowoff + col] = (unsigned short)f2bf(h);
      }
    }
  }
}

// ---------------- GEMM2: ent[row] = pw[row] * (act x down^T), plain stores ----------------
// block tile 128x64, BK=32, 4 waves 2x2, wave tile 64x32 (acc 4x2). 1024 active blocks.
__global__ __launch_bounds__(256, 4) void gemm2_kernel(
    const unsigned short* __restrict__ act,
    const unsigned short* __restrict__ dbw,
    const float* __restrict__ pw,
    const int* __restrict__ counts,
    const int* __restrict__ poff,
    float* __restrict__ ent)
{
  const int e = blockIdx.z;
  const int Ne = counts[e];
  const int mt = blockIdx.y;
  if (mt * 128 >= Ne) return;
  const int base = poff[e];
  const int n0 = blockIdx.x * 64;

  __shared__ __align__(16) unsigned short As[128 * 32];
  __shared__ __align__(16) unsigned short Bs[64 * 32];

  const int tid = threadIdx.x;
  const int lane = tid & 63;
  const int w = tid >> 6;
  const int wm = w >> 1, wn = w & 1;

  // A staging: 512 cells; wave w covers 128
  const int cA0 = w * 128 + lane, cA1 = cA0 + 64;
  const int mA0 = cA0 & 127, kqA0 = cA0 >> 7;
  const int mA1 = cA1 & 127, kqA1 = cA1 >> 7;
  const unsigned short* ga0 = act + (size_t)(base + mt * 128 + mA0) * I_DIM + kqA0 * 8;
  const unsigned short* ga1 = act + (size_t)(base + mt * 128 + mA1) * I_DIM + kqA1 * 8;
  unsigned short* lA0 = &As[(w * 128) * 8];
  unsigned short* lA1 = &As[(w * 128 + 64) * 8];

  // B staging: 256 cells; 1 ld16 per lane
  const int cB = w * 64 + lane;
  const int nB = cB & 63, kqB = cB >> 6;
  const unsigned short* gb = dbw + (size_t)e * H_DIM * I_DIM + (size_t)(n0 + nB) * I_DIM + kqB * 8;
  unsigned short* lB = &Bs[(w * 64) * 8];

  floatx4 zero = {0.f, 0.f, 0.f, 0.f};
  floatx4 acc[4][2];
#pragma unroll
  for (int i = 0; i < 4; i++)
#pragma unroll
    for (int j = 0; j < 2; j++) acc[i][j] = zero;

  const int quad = lane >> 4, lm = lane & 15;

  for (int k0 = 0; k0 < I_DIM; k0 += 32) {
    __syncthreads();
    ld16(ga0 + k0, lA0);
    ld16(ga1 + k0, lA1);
    ld16(gb + k0, lB);
    __syncthreads();
    bhalf8 a[4], b[2];
#pragma unroll
    for (int i = 0; i < 4; i++)
      a[i] = *(const bhalf8*)&As[(quad * 128 + wm * 64 + i * 16 + lm) * 8];
#pragma unroll
    for (int j = 0; j < 2; j++)
      b[j] = *(const bhalf8*)&Bs[(quad * 64 + wn * 32 + j * 16 + lm) * 8];
#pragma unroll
    for (int i = 0; i < 4; i++)
#pragma unroll
      for (int j = 0; j < 2; j++)
        acc[i][j] = __builtin_amdgcn_mfma_f32_16x16x32_bf16(a[i], b[j], acc[i][j], 0, 0, 0);
  }

  // epilogue: weighted plain stores into per-entry rows (no atomics)
#pragma unroll
  for (int i = 0; i < 4; i++) {
#pragma unroll
    for (int r = 0; r < 4; r++) {
      int row = mt * 128 + wm * 64 + i * 16 + quad * 4 + r;
      if (row < Ne) {
        float wt = pw[base + row];
        float* orow = ent + (size_t)(base + row) * H_DIM;
#pragma unroll
        for (int j = 0; j < 2; j++) {
          int col = n0 + wn * 32 + j * 16 + lm;
          orow[col] = wt * acc[i][j][r];
        }
      }
    }
  }
}

// ---------------- combine: out[t] = ent[inv[2t]] + ent[inv[2t+1]] ----------------
__global__ __launch_bounds__(256) void combine_kernel(
    const float* __restrict__ ent, const int* __restrict__ inv,
    float* __restrict__ out)
{
  const int t = blockIdx.x;
  const int p0 = inv[2 * t], p1 = inv[2 * t + 1];
  const float4* r0 = (const float4*)(ent + (size_t)p0 * H_DIM);
  const float4* r1 = (const float4*)(ent + (size_t)p1 * H_DIM);
  float4 a = r0[threadIdx.x], b = r1[threadIdx.x];
  float4 o = {a.x + b.x, a.y + b.y, a.z + b.z, a.w + b.w};
  ((float4*)(out + (size_t)t * H_DIM))[threadIdx.x] = o;
}

extern "C" void kernel_launch(void* const* d_in, const int* in_sizes, int n_in,
                              void* d_out, int out_size, void* d_ws, size_t ws_size,
                              hipStream_t stream) {
  const float* x    = (const float*)d_in[0];
  const int*   idx  = (const int*)d_in[1];
  const float* wts  = (const float*)d_in[2];
  const float* gate = (const float*)d_in[3];
  const float* up   = (const float*)d_in[4];
  const float* down = (const float*)d_in[5];
  float* out = (float*)d_out;
  char* ws = (char*)d_ws;

  // workspace layout (bytes). ent_out ALIASES gbw/ubw (dead after gemm1):
  unsigned short* xb  = (unsigned short*)(ws + 0);            //  8,388,608
  unsigned short* gbw = (unsigned short*)(ws + 8388608);      // 33,554,432
  unsigned short* ubw = (unsigned short*)(ws + 41943040);     // 33,554,432
  float*          ent = (float*)(ws + 8388608);               // 37,748,736 (CAP*H*4) aliases gbw+ubw head
  unsigned short* dbw = (unsigned short*)(ws + 75497472);     // 33,554,432
  unsigned short* act = (unsigned short*)(ws + 109051904);    // 37,748,736 (CAP*I*2)
  int*   perm   = (int*)(ws + 146800640);                     // 36,864
  float* pw     = (float*)(ws + 146837504);                   // 36,864
  int*   inv    = (int*)(ws + 146874368);                     // 32,768
  int*   counts = (int*)(ws + 146907136);                     // 32
  int*   poff   = (int*)(ws + 146907200);                     // 32

  route_kernel<<<1, 256, 0, stream>>>(idx, wts, perm, pw, inv, counts, poff);

  cast_kernel<<<(N_TOK * H_DIM) / (256 * 8), 256, 0, stream>>>(x, xb, N_TOK * H_DIM);
  cast_kernel<<<(N_EXP * I_DIM * H_DIM) / (256 * 8), 256, 0, stream>>>(gate, gbw, N_EXP * I_DIM * H_DIM);
  cast_kernel<<<(N_EXP * I_DIM * H_DIM) / (256 * 8), 256, 0, stream>>>(up, ubw, N_EXP * I_DIM * H_DIM);
  cast_kernel<<<(N_EXP * H_DIM * I_DIM) / (256 * 8), 256, 0, stream>>>(down, dbw, N_EXP * H_DIM * I_DIM);

  gemm1_kernel<<<dim3(I_DIM / 64, 64, N_EXP), 256, 0, stream>>>(
      xb, gbw, ubw, perm, counts, poff, act);

  gemm2_kernel<<<dim3(H_DIM / 64, 64, N_EXP), 256, 0, stream>>>(
      act, dbw, pw, counts, poff, ent);

  combine_kernel<<<N_TOK, 256, 0, stream>>>(ent, inv, out);
}

// Round 3
// 552.072 us; speedup vs baseline: 1.0057x; 1.0014x over previous
//
#include <hip/hip_runtime.h>

// MoE MLP: B=2,S=2048,H=1024,I=2048,E=8,TOPK=2  -> T=4096 tokens, 8192 entries.
// route -> fused cast fp32->bf16 -> gemm1(gate+up+silu, BK=64) -> gemm2(split-K=2, BK=64) -> combine.

#define H_DIM 1024
#define I_DIM 2048
#define N_EXP 8
#define N_TOK 4096
#define N_ENT 8192
#define CAP   9216   // 8192 + 8*128 padding capacity

typedef __attribute__((ext_vector_type(8))) short bhalf8;
typedef __attribute__((ext_vector_type(4))) float floatx4;

__device__ __forceinline__ unsigned short f2bf(float f) {
  unsigned int u = __float_as_uint(f);
  u += 0x7fffu + ((u >> 16) & 1u);   // round-to-nearest-even
  return (unsigned short)(u >> 16);
}

__device__ __forceinline__ void ld16(const void* g, void* l) {
  // async global->LDS, 16B per lane; LDS dst = wave-uniform base + lane*16
  __builtin_amdgcn_global_load_lds(
      (const __attribute__((address_space(1))) unsigned int*)g,
      (__attribute__((address_space(3))) unsigned int*)l, 16, 0, 0);
}

// ---------------- routing ----------------
__global__ __launch_bounds__(256) void route_kernel(
    const int* __restrict__ idx, const float* __restrict__ wts,
    int* __restrict__ perm, float* __restrict__ pw, int* __restrict__ inv,
    int* __restrict__ counts, int* __restrict__ poff)
{
  __shared__ int cnt[N_EXP], cur[N_EXP], off[N_EXP];
  const int t = threadIdx.x;
  if (t < N_EXP) { cnt[t] = 0; cur[t] = 0; }
  __syncthreads();
  for (int i = t; i < N_ENT; i += 256) atomicAdd(&cnt[idx[i] & 7], 1);
  __syncthreads();
  if (t == 0) {
    int o = 0;
    for (int e = 0; e < N_EXP; e++) {
      off[e] = o; counts[e] = cnt[e]; poff[e] = o;
      o += ((cnt[e] + 127) >> 7) << 7;
    }
  }
  __syncthreads();
  for (int i = t; i < N_ENT; i += 256) {
    int e = idx[i] & 7;
    int p = atomicAdd(&cur[e], 1);
    int pos = off[e] + p;
    perm[pos] = i >> 1;
    pw[pos] = wts[i];
    inv[i] = pos;
  }
}

// ---------------- fused fp32 -> bf16 cast over [x | gate | up | down] ----------------
// dst is one contiguous bf16 stream at ws+0. Segment sizes are multiples of 2048,
// so each 256-thread block maps entirely into one source tensor.
#define XE  4194304u
#define GE  20971520u
#define UE  37748736u
#define DE  54525952u
__global__ __launch_bounds__(256) void cast_all_kernel(
    const float* __restrict__ x, const float* __restrict__ g4,
    const float* __restrict__ u4, const float* __restrict__ d4,
    unsigned short* __restrict__ dst)
{
  unsigned int g = (blockIdx.x * 256u + threadIdx.x) * 8u;
  const float* s;
  if (g < XE)      s = x  + g;
  else if (g < GE) s = g4 + (g - XE);
  else if (g < UE) s = u4 + (g - GE);
  else             s = d4 + (g - UE);
  const float4* sp = (const float4*)s;
  float4 a = sp[0], b = sp[1];
  bhalf8 o;
  o[0] = (short)f2bf(a.x); o[1] = (short)f2bf(a.y); o[2] = (short)f2bf(a.z); o[3] = (short)f2bf(a.w);
  o[4] = (short)f2bf(b.x); o[5] = (short)f2bf(b.y); o[6] = (short)f2bf(b.z); o[7] = (short)f2bf(b.w);
  *(bhalf8*)(dst + g) = o;
}

// ---------------- GEMM1: act = silu(X Wg^T) * (X Wu^T), BK=64 ----------------
// block tile 128(M) x 64(N) x 2 matrices. 4 waves 2x2; wave tile 64x32 per matrix.
// LDS K-chunked: cell = kq*ROWS + r (kq in [0,8)), 16B/cell.
__global__ __launch_bounds__(256, 4) void gemm1_kernel(
    const unsigned short* __restrict__ xb,
    const unsigned short* __restrict__ gbw,
    const unsigned short* __restrict__ ubw,
    const int* __restrict__ perm,
    const int* __restrict__ counts,
    const int* __restrict__ poff,
    unsigned short* __restrict__ act)
{
  const int e = blockIdx.z;
  const int Ne = counts[e];
  const int mt = blockIdx.y;
  if (mt * 128 >= Ne) return;
  const int base = poff[e];
  const int n0 = blockIdx.x * 64;

  __shared__ __align__(16) unsigned short As[128 * 64];   // 16 KB
  __shared__ __align__(16) unsigned short Bgs[64 * 64];   //  8 KB
  __shared__ __align__(16) unsigned short Bus[64 * 64];   //  8 KB

  const int tid = threadIdx.x;
  const int lane = tid & 63;
  const int w = tid >> 6;
  const int wm = w >> 1, wn = w & 1;

  // A: 1024 cells (kq*128+m). wave w -> kq {2w,2w+1} x m {lane, 64+lane}
  int rr0 = mt * 128 + lane;      rr0 = rr0 < Ne ? rr0 : Ne - 1;
  int rr1 = mt * 128 + 64 + lane; rr1 = rr1 < Ne ? rr1 : Ne - 1;
  const int tok0 = perm[base + rr0];
  const int tok1 = perm[base + rr1];
  const unsigned short* pA0 = xb + (size_t)tok0 * H_DIM + 2 * w * 8;  // row lane
  const unsigned short* pA1 = xb + (size_t)tok1 * H_DIM + 2 * w * 8;  // row 64+lane
  unsigned short* lA_q0 = &As[(w * 256) * 8];
  unsigned short* lA_q1 = &As[(w * 256 + 64) * 8];
  unsigned short* lA_q2 = &As[(w * 256 + 128) * 8];
  unsigned short* lA_q3 = &As[(w * 256 + 192) * 8];

  // B: 512 cells (kq*64+n). wave w -> kq {2w,2w+1} x n = lane
  const size_t wbase = (size_t)e * I_DIM * H_DIM + (size_t)(n0 + lane) * H_DIM + 2 * w * 8;
  const unsigned short* pBg = gbw + wbase;
  const unsigned short* pBu = ubw + wbase;
  unsigned short* lBg0 = &Bgs[(w * 128) * 8];
  unsigned short* lBg1 = &Bgs[(w * 128 + 64) * 8];
  unsigned short* lBu0 = &Bus[(w * 128) * 8];
  unsigned short* lBu1 = &Bus[(w * 128 + 64) * 8];

  floatx4 zero = {0.f, 0.f, 0.f, 0.f};
  floatx4 accg[4][2], accu[4][2];
#pragma unroll
  for (int i = 0; i < 4; i++)
#pragma unroll
    for (int j = 0; j < 2; j++) { accg[i][j] = zero; accu[i][j] = zero; }

  const int quad = lane >> 4, lm = lane & 15;

  for (int k0 = 0; k0 < H_DIM; k0 += 64) {
    __syncthreads();
    ld16(pA0 + k0, lA_q0);      // (kq=2w,   m=lane)
    ld16(pA1 + k0, lA_q1);      // (kq=2w,   m=64+lane)
    ld16(pA0 + k0 + 8, lA_q2);  // (kq=2w+1, m=lane)
    ld16(pA1 + k0 + 8, lA_q3);  // (kq=2w+1, m=64+lane)
    ld16(pBg + k0, lBg0);
    ld16(pBg + k0 + 8, lBg1);
    ld16(pBu + k0, lBu0);
    ld16(pBu + k0 + 8, lBu1);
    __syncthreads();
#pragma unroll
    for (int kk = 0; kk < 2; kk++) {
      const int kq = kk * 4 + quad;
      bhalf8 a[4], bg[2], bu[2];
#pragma unroll
      for (int i = 0; i < 4; i++)
        a[i] = *(const bhalf8*)&As[(kq * 128 + wm * 64 + i * 16 + lm) * 8];
#pragma unroll
      for (int j = 0; j < 2; j++) {
        bg[j] = *(const bhalf8*)&Bgs[(kq * 64 + wn * 32 + j * 16 + lm) * 8];
        bu[j] = *(const bhalf8*)&Bus[(kq * 64 + wn * 32 + j * 16 + lm) * 8];
      }
#pragma unroll
      for (int i = 0; i < 4; i++)
#pragma unroll
        for (int j = 0; j < 2; j++) {
          accg[i][j] = __builtin_amdgcn_mfma_f32_16x16x32_bf16(a[i], bg[j], accg[i][j], 0, 0, 0);
          accu[i][j] = __builtin_amdgcn_mfma_f32_16x16x32_bf16(a[i], bu[j], accu[i][j], 0, 0, 0);
        }
    }
  }

#pragma unroll
  for (int i = 0; i < 4; i++) {
#pragma unroll
    for (int r = 0; r < 4; r++) {
      int row = mt * 128 + wm * 64 + i * 16 + quad * 4 + r;
      size_t rowoff = (size_t)(base + row) * I_DIM;
#pragma unroll
      for (int j = 0; j < 2; j++) {
        int col = n0 + wn * 32 + j * 16 + lm;
        float g = accg[i][j][r];
        float u = accu[i][j][r];
        float h = (g / (1.f + __expf(-g))) * u;
        act[rowoff + col] = (unsigned short)f2bf(h);
      }
    }
  }
}

// ---------------- GEMM2: ent[half][row] = pw[row]*(act x down^T over K-half), BK=64 ----------------
// block tile 128x128, split-K=2: blockIdx.x = (kh<<3)|nx. 1024 active blocks -> 4/CU.
__global__ __launch_bounds__(256, 4) void gemm2_kernel(
    const unsigned short* __restrict__ act,
    const unsigned short* __restrict__ dbw,
    const float* __restrict__ pw,
    const int* __restrict__ counts,
    const int* __restrict__ poff,
    float* __restrict__ ent)
{
  const int e = blockIdx.z;
  const int Ne = counts[e];
  const int mt = blockIdx.y;
  if (mt * 128 >= Ne) return;
  const int base = poff[e];
  const int n0 = (blockIdx.x & 7) * 128;
  const int k_lo = (blockIdx.x >> 3) * (I_DIM / 2);

  __shared__ __align__(16) unsigned short As[128 * 64];   // 16 KB
  __shared__ __align__(16) unsigned short Bs[128 * 64];   // 16 KB

  const int tid = threadIdx.x;
  const int lane = tid & 63;
  const int w = tid >> 6;
  const int wm = w >> 1, wn = w & 1;

  const unsigned short* pA0 = act + (size_t)(base + mt * 128 + lane) * I_DIM + k_lo + 2 * w * 8;
  const unsigned short* pA1 = act + (size_t)(base + mt * 128 + 64 + lane) * I_DIM + k_lo + 2 * w * 8;
  unsigned short* lA_q0 = &As[(w * 256) * 8];
  unsigned short* lA_q1 = &As[(w * 256 + 64) * 8];
  unsigned short* lA_q2 = &As[(w * 256 + 128) * 8];
  unsigned short* lA_q3 = &As[(w * 256 + 192) * 8];

  const unsigned short* pB0 = dbw + (size_t)e * H_DIM * I_DIM + (size_t)(n0 + lane) * I_DIM + k_lo + 2 * w * 8;
  const unsigned short* pB1 = dbw + (size_t)e * H_DIM * I_DIM + (size_t)(n0 + 64 + lane) * I_DIM + k_lo + 2 * w * 8;
  unsigned short* lB_q0 = &Bs[(w * 256) * 8];
  unsigned short* lB_q1 = &Bs[(w * 256 + 64) * 8];
  unsigned short* lB_q2 = &Bs[(w * 256 + 128) * 8];
  unsigned short* lB_q3 = &Bs[(w * 256 + 192) * 8];

  floatx4 zero = {0.f, 0.f, 0.f, 0.f};
  floatx4 acc[4][4];
#pragma unroll
  for (int i = 0; i < 4; i++)
#pragma unroll
    for (int j = 0; j < 4; j++) acc[i][j] = zero;

  const int quad = lane >> 4, lm = lane & 15;

  for (int k0 = 0; k0 < I_DIM / 2; k0 += 64) {
    __syncthreads();
    ld16(pA0 + k0, lA_q0);
    ld16(pA1 + k0, lA_q1);
    ld16(pA0 + k0 + 8, lA_q2);
    ld16(pA1 + k0 + 8, lA_q3);
    ld16(pB0 + k0, lB_q0);
    ld16(pB1 + k0, lB_q1);
    ld16(pB0 + k0 + 8, lB_q2);
    ld16(pB1 + k0 + 8, lB_q3);
    __syncthreads();
#pragma unroll
    for (int kk = 0; kk < 2; kk++) {
      const int kq = kk * 4 + quad;
      bhalf8 a[4], b[4];
#pragma unroll
      for (int i = 0; i < 4; i++)
        a[i] = *(const bhalf8*)&As[(kq * 128 + wm * 64 + i * 16 + lm) * 8];
#pragma unroll
      for (int j = 0; j < 4; j++)
        b[j] = *(const bhalf8*)&Bs[(kq * 128 + wn * 64 + j * 16 + lm) * 8];
#pragma unroll
      for (int i = 0; i < 4; i++)
#pragma unroll
        for (int j = 0; j < 4; j++)
          acc[i][j] = __builtin_amdgcn_mfma_f32_16x16x32_bf16(a[i], b[j], acc[i][j], 0, 0, 0);
    }
  }

  float* enth = ent + (size_t)(blockIdx.x >> 3) * CAP * H_DIM;
#pragma unroll
  for (int i = 0; i < 4; i++) {
#pragma unroll
    for (int r = 0; r < 4; r++) {
      int row = mt * 128 + wm * 64 + i * 16 + quad * 4 + r;
      if (row < Ne) {
        float wt = pw[base + row];
        float* orow = enth + (size_t)(base + row) * H_DIM;
#pragma unroll
        for (int j = 0; j < 4; j++) {
          int col = n0 + wn * 64 + j * 16 + lm;
          orow[col] = wt * acc[i][j][r];
        }
      }
    }
  }
}

// ---------------- combine: out[t] = sum over 2 entries x 2 K-halves ----------------
__global__ __launch_bounds__(256) void combine_kernel(
    const float* __restrict__ ent, const int* __restrict__ inv,
    float* __restrict__ out)
{
  const int t = blockIdx.x;
  const int p0 = inv[2 * t], p1 = inv[2 * t + 1];
  const float4* r0 = (const float4*)(ent + (size_t)p0 * H_DIM);
  const float4* r1 = (const float4*)(ent + (size_t)p1 * H_DIM);
  const float4* r2 = (const float4*)(ent + (size_t)(CAP + p0) * H_DIM);
  const float4* r3 = (const float4*)(ent + (size_t)(CAP + p1) * H_DIM);
  float4 a = r0[threadIdx.x], b = r1[threadIdx.x];
  float4 c = r2[threadIdx.x], d = r3[threadIdx.x];
  float4 o = {a.x + b.x + c.x + d.x, a.y + b.y + c.y + d.y,
              a.z + b.z + c.z + d.z, a.w + b.w + c.w + d.w};
  ((float4*)(out + (size_t)t * H_DIM))[threadIdx.x] = o;
}

extern "C" void kernel_launch(void* const* d_in, const int* in_sizes, int n_in,
                              void* d_out, int out_size, void* d_ws, size_t ws_size,
                              hipStream_t stream) {
  const float* x    = (const float*)d_in[0];
  const int*   idx  = (const int*)d_in[1];
  const float* wts  = (const float*)d_in[2];
  const float* gate = (const float*)d_in[3];
  const float* up   = (const float*)d_in[4];
  const float* down = (const float*)d_in[5];
  float* out = (float*)d_out;
  char* ws = (char*)d_ws;

  // workspace layout (bytes). bf16 stream [xb|gbw|ubw|dbw] contiguous at 0.
  // ent (2*CAP*H fp32 = 75,497,472) ALIASES [xb|gbw|ubw] exactly (dead after gemm1).
  unsigned short* bfs = (unsigned short*)(ws + 0);
  unsigned short* xb  = (unsigned short*)(ws + 0);            //  8,388,608
  unsigned short* gbw = (unsigned short*)(ws + 8388608);      // 33,554,432
  unsigned short* ubw = (unsigned short*)(ws + 41943040);     // 33,554,432
  unsigned short* dbw = (unsigned short*)(ws + 75497472);     // 33,554,432
  float*          ent = (float*)(ws + 0);                     // 75,497,472 (2*CAP*H*4)
  unsigned short* act = (unsigned short*)(ws + 109051904);    // 37,748,736 (CAP*I*2)
  int*   perm   = (int*)(ws + 146800640);                     // 36,864
  float* pw     = (float*)(ws + 146837504);                   // 36,864
  int*   inv    = (int*)(ws + 146874368);                     // 32,768
  int*   counts = (int*)(ws + 146907136);                     // 32
  int*   poff   = (int*)(ws + 146907200);                     // 32

  route_kernel<<<1, 256, 0, stream>>>(idx, wts, perm, pw, inv, counts, poff);

  cast_all_kernel<<<DE / 2048, 256, 0, stream>>>(x, gate, up, down, bfs);

  gemm1_kernel<<<dim3(I_DIM / 64, 64, N_EXP), 256, 0, stream>>>(
      xb, gbw, ubw, perm, counts, poff, act);

  gemm2_kernel<<<dim3(16, 64, N_EXP), 256, 0, stream>>>(
      act, dbw, pw, counts, poff, ent);

  combine_kernel<<<N_TOK, 256, 0, stream>>>(ent, inv, out);
}

// Round 4
// 540.177 us; speedup vs baseline: 1.0278x; 1.0220x over previous
//
#include <hip/hip_runtime.h>

// MoE MLP: B=2,S=2048,H=1024,I=2048,E=8,TOPK=2  -> T=4096 tokens, 8192 entries.
// route -> fused cast -> gemm1(gate+up+silu) -> gemm2(split-K=2) -> combine.
// R4: XOR-swizzled global_load_lds staging: each ld16 reads 8 FULL 128B lines
// (coalesced) instead of 64 scattered 16B chunks; LDS cell (m,c) holds chunk c^(m&7).

#define H_DIM 1024
#define I_DIM 2048
#define N_EXP 8
#define N_TOK 4096
#define N_ENT 8192
#define CAP   9216   // 8192 + 8*128 padding capacity

typedef __attribute__((ext_vector_type(8))) short bhalf8;
typedef __attribute__((ext_vector_type(4))) float floatx4;

__device__ __forceinline__ unsigned short f2bf(float f) {
  unsigned int u = __float_as_uint(f);
  u += 0x7fffu + ((u >> 16) & 1u);
  return (unsigned short)(u >> 16);
}

__device__ __forceinline__ void ld16(const void* g, void* l) {
  __builtin_amdgcn_global_load_lds(
      (const __attribute__((address_space(1))) unsigned int*)g,
      (__attribute__((address_space(3))) unsigned int*)l, 16, 0, 0);
}

// ---------------- routing ----------------
__global__ __launch_bounds__(256) void route_kernel(
    const int* __restrict__ idx, const float* __restrict__ wts,
    int* __restrict__ perm, float* __restrict__ pw, int* __restrict__ inv,
    int* __restrict__ counts, int* __restrict__ poff)
{
  __shared__ int cnt[N_EXP], cur[N_EXP], off[N_EXP];
  const int t = threadIdx.x;
  if (t < N_EXP) { cnt[t] = 0; cur[t] = 0; }
  __syncthreads();
  for (int i = t; i < N_ENT; i += 256) atomicAdd(&cnt[idx[i] & 7], 1);
  __syncthreads();
  if (t == 0) {
    int o = 0;
    for (int e = 0; e < N_EXP; e++) {
      off[e] = o; counts[e] = cnt[e]; poff[e] = o;
      o += ((cnt[e] + 127) >> 7) << 7;
    }
  }
  __syncthreads();
  for (int i = t; i < N_ENT; i += 256) {
    int e = idx[i] & 7;
    int p = atomicAdd(&cur[e], 1);
    int pos = off[e] + p;
    perm[pos] = i >> 1;
    pw[pos] = wts[i];
    inv[i] = pos;
  }
}

// ---------------- fused fp32 -> bf16 cast over [x | gate | up | down] ----------------
#define XE  4194304u
#define GE  20971520u
#define UE  37748736u
#define DE  54525952u
__global__ __launch_bounds__(256) void cast_all_kernel(
    const float* __restrict__ x, const float* __restrict__ g4,
    const float* __restrict__ u4, const float* __restrict__ d4,
    unsigned short* __restrict__ dst)
{
  unsigned int g = (blockIdx.x * 256u + threadIdx.x) * 8u;
  const float* s;
  if (g < XE)      s = x  + g;
  else if (g < GE) s = g4 + (g - XE);
  else if (g < UE) s = u4 + (g - GE);
  else             s = d4 + (g - UE);
  const float4* sp = (const float4*)s;
  float4 a = sp[0], b = sp[1];
  bhalf8 o;
  o[0] = (short)f2bf(a.x); o[1] = (short)f2bf(a.y); o[2] = (short)f2bf(a.z); o[3] = (short)f2bf(a.w);
  o[4] = (short)f2bf(b.x); o[5] = (short)f2bf(b.y); o[6] = (short)f2bf(b.z); o[7] = (short)f2bf(b.w);
  *(bhalf8*)(dst + g) = o;
}

// ---------------- GEMM1: act = silu(X Wg^T) * (X Wu^T), BK=64, swizzled staging ----------
// block tile 128(M) x 64(N) x 2 matrices. 4 waves 2x2; wave tile 64x32 per matrix.
// LDS row-major: row m = 8 cells x 16B; cell c holds K-chunk c^(m&7).
__global__ __launch_bounds__(256, 4) void gemm1_kernel(
    const unsigned short* __restrict__ xb,
    const unsigned short* __restrict__ gbw,
    const unsigned short* __restrict__ ubw,
    const int* __restrict__ perm,
    const int* __restrict__ counts,
    const int* __restrict__ poff,
    unsigned short* __restrict__ act)
{
  const int e = blockIdx.z;
  const int Ne = counts[e];
  const int mt = blockIdx.y;
  if (mt * 128 >= Ne) return;
  const int base = poff[e];
  const int n0 = blockIdx.x * 64;

  __shared__ __align__(16) unsigned short As[128 * 64];   // 16 KB
  __shared__ __align__(16) unsigned short Bgs[64 * 64];   //  8 KB
  __shared__ __align__(16) unsigned short Bus[64 * 64];   //  8 KB

  const int tid = threadIdx.x;
  const int lane = tid & 63;
  const int w = tid >> 6;
  const int wm = w >> 1, wn = w & 1;
  const int i3 = lane >> 3, i7 = lane & 7;
  const int swc = (i7 ^ i3) * 8;    // swizzled K-chunk offset (elements)

  // A: 16 instrs (8 rows each); wave w does t=0..3 covering rows w*32..w*32+31
  const unsigned short* pA[4]; unsigned short* lA[4];
#pragma unroll
  for (int t = 0; t < 4; t++) {
    int rloc = w * 32 + t * 8 + i3;
    int rr = mt * 128 + rloc; rr = rr < Ne ? rr : Ne - 1;
    pA[t] = xb + (size_t)perm[base + rr] * H_DIM + swc;
    lA[t] = &As[(w * 32 + t * 8) * 64];
  }
  // B: 8 instrs each; wave w does t=0..1 covering rows w*16..w*16+15
  const unsigned short* pBg[2]; const unsigned short* pBu[2];
  unsigned short* lBg[2]; unsigned short* lBu[2];
#pragma unroll
  for (int t = 0; t < 2; t++) {
    int nloc = w * 16 + t * 8 + i3;
    size_t wb = (size_t)e * (I_DIM * H_DIM) + (size_t)(n0 + nloc) * H_DIM + swc;
    pBg[t] = gbw + wb;
    pBu[t] = ubw + wb;
    lBg[t] = &Bgs[(w * 16 + t * 8) * 64];
    lBu[t] = &Bus[(w * 16 + t * 8) * 64];
  }

  floatx4 zero = {0.f, 0.f, 0.f, 0.f};
  floatx4 accg[4][2], accu[4][2];
#pragma unroll
  for (int i = 0; i < 4; i++)
#pragma unroll
    for (int j = 0; j < 2; j++) { accg[i][j] = zero; accu[i][j] = zero; }

  const int quad = lane >> 4, lm = lane & 15;
  const int s7 = lm & 7;

  for (int k0 = 0; k0 < H_DIM; k0 += 64) {
    __syncthreads();
#pragma unroll
    for (int t = 0; t < 4; t++) ld16(pA[t] + k0, lA[t]);
#pragma unroll
    for (int t = 0; t < 2; t++) { ld16(pBg[t] + k0, lBg[t]); ld16(pBu[t] + k0, lBu[t]); }
    __syncthreads();
#pragma unroll
    for (int kk = 0; kk < 2; kk++) {
      const int kq = kk * 4 + quad;
      const int ko = (kq ^ s7) * 8;
      bhalf8 a[4], bg[2], bu[2];
#pragma unroll
      for (int i = 0; i < 4; i++)
        a[i] = *(const bhalf8*)&As[(wm * 64 + i * 16 + lm) * 64 + ko];
#pragma unroll
      for (int j = 0; j < 2; j++) {
        bg[j] = *(const bhalf8*)&Bgs[(wn * 32 + j * 16 + lm) * 64 + ko];
        bu[j] = *(const bhalf8*)&Bus[(wn * 32 + j * 16 + lm) * 64 + ko];
      }
#pragma unroll
      for (int i = 0; i < 4; i++)
#pragma unroll
        for (int j = 0; j < 2; j++) {
          accg[i][j] = __builtin_amdgcn_mfma_f32_16x16x32_bf16(a[i], bg[j], accg[i][j], 0, 0, 0);
          accu[i][j] = __builtin_amdgcn_mfma_f32_16x16x32_bf16(a[i], bu[j], accu[i][j], 0, 0, 0);
        }
    }
  }

#pragma unroll
  for (int i = 0; i < 4; i++) {
#pragma unroll
    for (int r = 0; r < 4; r++) {
      int row = mt * 128 + wm * 64 + i * 16 + quad * 4 + r;
      size_t rowoff = (size_t)(base + row) * I_DIM;
#pragma unroll
      for (int j = 0; j < 2; j++) {
        int col = n0 + wn * 32 + j * 16 + lm;
        float g = accg[i][j][r];
        float u = accu[i][j][r];
        float h = (g / (1.f + __expf(-g))) * u;
        act[rowoff + col] = (unsigned short)f2bf(h);
      }
    }
  }
}

// ---------------- GEMM2: ent[half][row] = pw[row]*(act x down^T over K-half) ----------------
// block tile 128x128, BK=64, split-K=2: blockIdx.x = (kh<<3)|nx. Swizzled staging.
__global__ __launch_bounds__(256, 4) void gemm2_kernel(
    const unsigned short* __restrict__ act,
    const unsigned short* __restrict__ dbw,
    const float* __restrict__ pw,
    const int* __restrict__ counts,
    const int* __restrict__ poff,
    float* __restrict__ ent)
{
  const int e = blockIdx.z;
  const int Ne = counts[e];
  const int mt = blockIdx.y;
  if (mt * 128 >= Ne) return;
  const int base = poff[e];
  const int n0 = (blockIdx.x & 7) * 128;
  const int k_lo = (blockIdx.x >> 3) * (I_DIM / 2);

  __shared__ __align__(16) unsigned short As[128 * 64];   // 16 KB
  __shared__ __align__(16) unsigned short Bs[128 * 64];   // 16 KB

  const int tid = threadIdx.x;
  const int lane = tid & 63;
  const int w = tid >> 6;
  const int wm = w >> 1, wn = w & 1;
  const int i3 = lane >> 3, i7 = lane & 7;
  const int swc = (i7 ^ i3) * 8;

  const unsigned short* pA[4]; unsigned short* lA[4];
  const unsigned short* pB[4]; unsigned short* lB[4];
#pragma unroll
  for (int t = 0; t < 4; t++) {
    int rloc = w * 32 + t * 8 + i3;
    pA[t] = act + (size_t)(base + mt * 128 + rloc) * I_DIM + k_lo + swc;
    lA[t] = &As[(w * 32 + t * 8) * 64];
    pB[t] = dbw + (size_t)e * (H_DIM * I_DIM) + (size_t)(n0 + rloc) * I_DIM + k_lo + swc;
    lB[t] = &Bs[(w * 32 + t * 8) * 64];
  }

  floatx4 zero = {0.f, 0.f, 0.f, 0.f};
  floatx4 acc[4][4];
#pragma unroll
  for (int i = 0; i < 4; i++)
#pragma unroll
    for (int j = 0; j < 4; j++) acc[i][j] = zero;

  const int quad = lane >> 4, lm = lane & 15;
  const int s7 = lm & 7;

  for (int k0 = 0; k0 < I_DIM / 2; k0 += 64) {
    __syncthreads();
#pragma unroll
    for (int t = 0; t < 4; t++) { ld16(pA[t] + k0, lA[t]); ld16(pB[t] + k0, lB[t]); }
    __syncthreads();
#pragma unroll
    for (int kk = 0; kk < 2; kk++) {
      const int kq = kk * 4 + quad;
      const int ko = (kq ^ s7) * 8;
      bhalf8 a[4], b[4];
#pragma unroll
      for (int i = 0; i < 4; i++)
        a[i] = *(const bhalf8*)&As[(wm * 64 + i * 16 + lm) * 64 + ko];
#pragma unroll
      for (int j = 0; j < 4; j++)
        b[j] = *(const bhalf8*)&Bs[(wn * 64 + j * 16 + lm) * 64 + ko];
#pragma unroll
      for (int i = 0; i < 4; i++)
#pragma unroll
        for (int j = 0; j < 4; j++)
          acc[i][j] = __builtin_amdgcn_mfma_f32_16x16x32_bf16(a[i], b[j], acc[i][j], 0, 0, 0);
    }
  }

  float* enth = ent + (size_t)(blockIdx.x >> 3) * CAP * H_DIM;
#pragma unroll
  for (int i = 0; i < 4; i++) {
#pragma unroll
    for (int r = 0; r < 4; r++) {
      int row = mt * 128 + wm * 64 + i * 16 + quad * 4 + r;
      if (row < Ne) {
        float wt = pw[base + row];
        float* orow = enth + (size_t)(base + row) * H_DIM;
#pragma unroll
        for (int j = 0; j < 4; j++) {
          int col = n0 + wn * 64 + j * 16 + lm;
          orow[col] = wt * acc[i][j][r];
        }
      }
    }
  }
}

// ---------------- combine ----------------
__global__ __launch_bounds__(256) void combine_kernel(
    const float* __restrict__ ent, const int* __restrict__ inv,
    float* __restrict__ out)
{
  const int t = blockIdx.x;
  const int p0 = inv[2 * t], p1 = inv[2 * t + 1];
  const float4* r0 = (const float4*)(ent + (size_t)p0 * H_DIM);
  const float4* r1 = (const float4*)(ent + (size_t)p1 * H_DIM);
  const float4* r2 = (const float4*)(ent + (size_t)(CAP + p0) * H_DIM);
  const float4* r3 = (const float4*)(ent + (size_t)(CAP + p1) * H_DIM);
  float4 a = r0[threadIdx.x], b = r1[threadIdx.x];
  float4 c = r2[threadIdx.x], d = r3[threadIdx.x];
  float4 o = {a.x + b.x + c.x + d.x, a.y + b.y + c.y + d.y,
              a.z + b.z + c.z + d.z, a.w + b.w + c.w + d.w};
  ((float4*)(out + (size_t)t * H_DIM))[threadIdx.x] = o;
}

extern "C" void kernel_launch(void* const* d_in, const int* in_sizes, int n_in,
                              void* d_out, int out_size, void* d_ws, size_t ws_size,
                              hipStream_t stream) {
  const float* x    = (const float*)d_in[0];
  const int*   idx  = (const int*)d_in[1];
  const float* wts  = (const float*)d_in[2];
  const float* gate = (const float*)d_in[3];
  const float* up   = (const float*)d_in[4];
  const float* down = (const float*)d_in[5];
  float* out = (float*)d_out;
  char* ws = (char*)d_ws;

  unsigned short* bfs = (unsigned short*)(ws + 0);
  unsigned short* xb  = (unsigned short*)(ws + 0);            //  8,388,608
  unsigned short* gbw = (unsigned short*)(ws + 8388608);      // 33,554,432
  unsigned short* ubw = (unsigned short*)(ws + 41943040);     // 33,554,432
  unsigned short* dbw = (unsigned short*)(ws + 75497472);     // 33,554,432
  float*          ent = (float*)(ws + 0);                     // 75,497,472 (aliases xb|gbw|ubw)
  unsigned short* act = (unsigned short*)(ws + 109051904);    // 37,748,736
  int*   perm   = (int*)(ws + 146800640);
  float* pw     = (float*)(ws + 146837504);
  int*   inv    = (int*)(ws + 146874368);
  int*   counts = (int*)(ws + 146907136);
  int*   poff   = (int*)(ws + 146907200);

  route_kernel<<<1, 256, 0, stream>>>(idx, wts, perm, pw, inv, counts, poff);

  cast_all_kernel<<<DE / 2048, 256, 0, stream>>>(x, gate, up, down, bfs);

  gemm1_kernel<<<dim3(I_DIM / 64, 64, N_EXP), 256, 0, stream>>>(
      xb, gbw, ubw, perm, counts, poff, act);

  gemm2_kernel<<<dim3(16, 64, N_EXP), 256, 0, stream>>>(
      act, dbw, pw, counts, poff, ent);

  combine_kernel<<<N_TOK, 256, 0, stream>>>(ent, inv, out);
}

// Round 5
// 427.420 us; speedup vs baseline: 1.2990x; 1.2638x over previous
//
#include <hip/hip_runtime.h>

// MoE MLP: B=2,S=2048,H=1024,I=2048,E=8,TOPK=2  -> T=4096 tokens, 8192 entries.
// route -> fused cast -> gemm1(gate+up+silu) -> gemm2(split-K=2) -> combine.
// R5: M=256 tiles, 512-thread blocks -> 85 FLOP/staged-byte (was 64); fewer
// B-restreams per expert. XOR-swizzled coalesced global_load_lds staging kept.

#define H_DIM 1024
#define I_DIM 2048
#define N_EXP 8
#define N_TOK 4096
#define N_ENT 8192
#define CAP   9216   // 8192 + 8*128 padding capacity (segments padded to 128)

typedef __attribute__((ext_vector_type(8))) short bhalf8;
typedef __attribute__((ext_vector_type(4))) float floatx4;

__device__ __forceinline__ unsigned short f2bf(float f) {
  unsigned int u = __float_as_uint(f);
  u += 0x7fffu + ((u >> 16) & 1u);
  return (unsigned short)(u >> 16);
}

__device__ __forceinline__ void ld16(const void* g, void* l) {
  __builtin_amdgcn_global_load_lds(
      (const __attribute__((address_space(1))) unsigned int*)g,
      (__attribute__((address_space(3))) unsigned int*)l, 16, 0, 0);
}

// ---------------- routing ----------------
__global__ __launch_bounds__(256) void route_kernel(
    const int* __restrict__ idx, const float* __restrict__ wts,
    int* __restrict__ perm, float* __restrict__ pw, int* __restrict__ inv,
    int* __restrict__ counts, int* __restrict__ poff)
{
  __shared__ int cnt[N_EXP], cur[N_EXP], off[N_EXP];
  const int t = threadIdx.x;
  if (t < N_EXP) { cnt[t] = 0; cur[t] = 0; }
  __syncthreads();
  for (int i = t; i < N_ENT; i += 256) atomicAdd(&cnt[idx[i] & 7], 1);
  __syncthreads();
  if (t == 0) {
    int o = 0;
    for (int e = 0; e < N_EXP; e++) {
      off[e] = o; counts[e] = cnt[e]; poff[e] = o;
      o += ((cnt[e] + 127) >> 7) << 7;
    }
  }
  __syncthreads();
  for (int i = t; i < N_ENT; i += 256) {
    int e = idx[i] & 7;
    int p = atomicAdd(&cur[e], 1);
    int pos = off[e] + p;
    perm[pos] = i >> 1;
    pw[pos] = wts[i];
    inv[i] = pos;
  }
}

// ---------------- fused fp32 -> bf16 cast over [x | gate | up | down] ----------------
#define XE  4194304u
#define GE  20971520u
#define UE  37748736u
#define DE  54525952u
__global__ __launch_bounds__(256) void cast_all_kernel(
    const float* __restrict__ x, const float* __restrict__ g4,
    const float* __restrict__ u4, const float* __restrict__ d4,
    unsigned short* __restrict__ dst)
{
  unsigned int g = (blockIdx.x * 256u + threadIdx.x) * 8u;
  const float* s;
  if (g < XE)      s = x  + g;
  else if (g < GE) s = g4 + (g - XE);
  else if (g < UE) s = u4 + (g - GE);
  else             s = d4 + (g - UE);
  const float4* sp = (const float4*)s;
  float4 a = sp[0], b = sp[1];
  bhalf8 o;
  o[0] = (short)f2bf(a.x); o[1] = (short)f2bf(a.y); o[2] = (short)f2bf(a.z); o[3] = (short)f2bf(a.w);
  o[4] = (short)f2bf(b.x); o[5] = (short)f2bf(b.y); o[6] = (short)f2bf(b.z); o[7] = (short)f2bf(b.w);
  *(bhalf8*)(dst + g) = o;
}

// ---------------- GEMM1: act = silu(X Wg^T) * (X Wu^T) ----------------
// 512 threads, block tile 256(M) x 64(N) x 2 matrices, BK=64.
// 8 waves as 4m x 2n; wave tile 64x32 per matrix (accg/accu 4x2).
// LDS row-major: row m = 8 cells x 16B; cell c holds K-chunk c^(m&7).
__global__ __launch_bounds__(512, 4) void gemm1_kernel(
    const unsigned short* __restrict__ xb,
    const unsigned short* __restrict__ gbw,
    const unsigned short* __restrict__ ubw,
    const int* __restrict__ perm,
    const int* __restrict__ counts,
    const int* __restrict__ poff,
    unsigned short* __restrict__ act)
{
  const int e = blockIdx.z;
  const int Ne = counts[e];
  const int mt = blockIdx.y;
  if (mt * 256 >= Ne) return;
  const int NeR = ((Ne + 127) >> 7) << 7;   // padded segment length
  const int base = poff[e];
  const int n0 = blockIdx.x * 64;

  __shared__ __align__(16) unsigned short As[256 * 64];   // 32 KB
  __shared__ __align__(16) unsigned short Bgs[64 * 64];   //  8 KB
  __shared__ __align__(16) unsigned short Bus[64 * 64];   //  8 KB

  const int tid = threadIdx.x;
  const int lane = tid & 63;
  const int w = tid >> 6;          // 0..7
  const int wmi = w >> 1;          // 0..3 (M)
  const int wnj = w & 1;           // 0..1 (N)
  const int i3 = lane >> 3, i7 = lane & 7;
  const int swc = (i7 ^ i3) * 8;   // swizzled K-chunk offset (elements)

  // A: 4 ld16/wave -> 32 rows
  const unsigned short* pA[4]; unsigned short* lA[4];
#pragma unroll
  for (int t = 0; t < 4; t++) {
    int rloc = w * 32 + t * 8 + i3;
    int rr = mt * 256 + rloc; rr = rr < Ne ? rr : Ne - 1;
    pA[t] = xb + (size_t)perm[base + rr] * H_DIM + swc;
    lA[t] = &As[(w * 32 + t * 8) * 64];
  }
  // B: 1 ld16 each per wave -> 8 rows
  const int nloc = w * 8 + i3;
  const size_t wb = (size_t)e * (I_DIM * H_DIM) + (size_t)(n0 + nloc) * H_DIM + swc;
  const unsigned short* pBg = gbw + wb;
  const unsigned short* pBu = ubw + wb;
  unsigned short* lBg = &Bgs[(w * 8) * 64];
  unsigned short* lBu = &Bus[(w * 8) * 64];

  floatx4 zero = {0.f, 0.f, 0.f, 0.f};
  floatx4 accg[4][2], accu[4][2];
#pragma unroll
  for (int i = 0; i < 4; i++)
#pragma unroll
    for (int j = 0; j < 2; j++) { accg[i][j] = zero; accu[i][j] = zero; }

  const int quad = lane >> 4, lm = lane & 15;
  const int s7 = lm & 7;

  for (int k0 = 0; k0 < H_DIM; k0 += 64) {
    __syncthreads();
#pragma unroll
    for (int t = 0; t < 4; t++) ld16(pA[t] + k0, lA[t]);
    ld16(pBg + k0, lBg);
    ld16(pBu + k0, lBu);
    __syncthreads();
#pragma unroll
    for (int kk = 0; kk < 2; kk++) {
      const int kq = kk * 4 + quad;
      const int ko = (kq ^ s7) * 8;
      bhalf8 a[4], bg[2], bu[2];
#pragma unroll
      for (int i = 0; i < 4; i++)
        a[i] = *(const bhalf8*)&As[(wmi * 64 + i * 16 + lm) * 64 + ko];
#pragma unroll
      for (int j = 0; j < 2; j++) {
        bg[j] = *(const bhalf8*)&Bgs[(wnj * 32 + j * 16 + lm) * 64 + ko];
        bu[j] = *(const bhalf8*)&Bus[(wnj * 32 + j * 16 + lm) * 64 + ko];
      }
#pragma unroll
      for (int i = 0; i < 4; i++)
#pragma unroll
        for (int j = 0; j < 2; j++) {
          accg[i][j] = __builtin_amdgcn_mfma_f32_16x16x32_bf16(a[i], bg[j], accg[i][j], 0, 0, 0);
          accu[i][j] = __builtin_amdgcn_mfma_f32_16x16x32_bf16(a[i], bu[j], accu[i][j], 0, 0, 0);
        }
    }
  }

  // epilogue: stores clamped to the padded segment (row < NeR). Rows in the
  // 256-tile beyond NeR are left as poison; gemm2 computes-and-discards them.
#pragma unroll
  for (int i = 0; i < 4; i++) {
#pragma unroll
    for (int r = 0; r < 4; r++) {
      int row = mt * 256 + wmi * 64 + i * 16 + quad * 4 + r;
      if (row < NeR) {
        size_t rowoff = (size_t)(base + row) * I_DIM;
#pragma unroll
        for (int j = 0; j < 2; j++) {
          int col = n0 + wnj * 32 + j * 16 + lm;
          float g = accg[i][j][r];
          float u = accu[i][j][r];
          float h = (g / (1.f + __expf(-g))) * u;
          act[rowoff + col] = (unsigned short)f2bf(h);
        }
      }
    }
  }
}

// ---------------- GEMM2: ent[half][row] = pw[row]*(act x down^T over K-half) ----------------
// 512 threads, block tile 256x128, BK=64, split-K=2: blockIdx.x = (kh<<3)|nx.
// 8 waves 4m x 2n; wave tile 64x64 (acc 4x4).
__global__ __launch_bounds__(512, 4) void gemm2_kernel(
    const unsigned short* __restrict__ act,
    const unsigned short* __restrict__ dbw,
    const float* __restrict__ pw,
    const int* __restrict__ counts,
    const int* __restrict__ poff,
    float* __restrict__ ent)
{
  const int e = blockIdx.z;
  const int Ne = counts[e];
  const int mt = blockIdx.y;
  if (mt * 256 >= Ne) return;
  const int NeR = ((Ne + 127) >> 7) << 7;
  const int base = poff[e];
  const int n0 = (blockIdx.x & 7) * 128;
  const int k_lo = (blockIdx.x >> 3) * (I_DIM / 2);

  __shared__ __align__(16) unsigned short As[256 * 64];   // 32 KB
  __shared__ __align__(16) unsigned short Bs[128 * 64];   // 16 KB

  const int tid = threadIdx.x;
  const int lane = tid & 63;
  const int w = tid >> 6;
  const int wmi = w >> 1, wnj = w & 1;
  const int i3 = lane >> 3, i7 = lane & 7;
  const int swc = (i7 ^ i3) * 8;

  // A: 4 ld16/wave; clamp rows to the padded segment (poison rows are discarded later)
  const unsigned short* pA[4]; unsigned short* lA[4];
#pragma unroll
  for (int t = 0; t < 4; t++) {
    int rloc = w * 32 + t * 8 + i3;
    int rr = mt * 256 + rloc; rr = rr < NeR ? rr : NeR - 1;
    pA[t] = act + (size_t)(base + rr) * I_DIM + k_lo + swc;
    lA[t] = &As[(w * 32 + t * 8) * 64];
  }
  // B: 2 ld16/wave -> 16 rows
  const unsigned short* pB[2]; unsigned short* lB[2];
#pragma unroll
  for (int t = 0; t < 2; t++) {
    int rloc = w * 16 + t * 8 + i3;
    pB[t] = dbw + (size_t)e * (H_DIM * I_DIM) + (size_t)(n0 + rloc) * I_DIM + k_lo + swc;
    lB[t] = &Bs[(w * 16 + t * 8) * 64];
  }

  floatx4 zero = {0.f, 0.f, 0.f, 0.f};
  floatx4 acc[4][4];
#pragma unroll
  for (int i = 0; i < 4; i++)
#pragma unroll
    for (int j = 0; j < 4; j++) acc[i][j] = zero;

  const int quad = lane >> 4, lm = lane & 15;
  const int s7 = lm & 7;

  for (int k0 = 0; k0 < I_DIM / 2; k0 += 64) {
    __syncthreads();
#pragma unroll
    for (int t = 0; t < 4; t++) ld16(pA[t] + k0, lA[t]);
#pragma unroll
    for (int t = 0; t < 2; t++) ld16(pB[t] + k0, lB[t]);
    __syncthreads();
#pragma unroll
    for (int kk = 0; kk < 2; kk++) {
      const int kq = kk * 4 + quad;
      const int ko = (kq ^ s7) * 8;
      bhalf8 a[4], b[4];
#pragma unroll
      for (int i = 0; i < 4; i++)
        a[i] = *(const bhalf8*)&As[(wmi * 64 + i * 16 + lm) * 64 + ko];
#pragma unroll
      for (int j = 0; j < 4; j++)
        b[j] = *(const bhalf8*)&Bs[(wnj * 64 + j * 16 + lm) * 64 + ko];
#pragma unroll
      for (int i = 0; i < 4; i++)
#pragma unroll
        for (int j = 0; j < 4; j++)
          acc[i][j] = __builtin_amdgcn_mfma_f32_16x16x32_bf16(a[i], b[j], acc[i][j], 0, 0, 0);
    }
  }

  float* enth = ent + (size_t)(blockIdx.x >> 3) * CAP * H_DIM;
#pragma unroll
  for (int i = 0; i < 4; i++) {
#pragma unroll
    for (int r = 0; r < 4; r++) {
      int row = mt * 256 + wmi * 64 + i * 16 + quad * 4 + r;
      if (row < Ne) {
        float wt = pw[base + row];
        float* orow = enth + (size_t)(base + row) * H_DIM;
#pragma unroll
        for (int j = 0; j < 4; j++) {
          int col = n0 + wnj * 64 + j * 16 + lm;
          orow[col] = wt * acc[i][j][r];
        }
      }
    }
  }
}

// ---------------- combine ----------------
__global__ __launch_bounds__(256) void combine_kernel(
    const float* __restrict__ ent, const int* __restrict__ inv,
    float* __restrict__ out)
{
  const int t = blockIdx.x;
  const int p0 = inv[2 * t], p1 = inv[2 * t + 1];
  const float4* r0 = (const float4*)(ent + (size_t)p0 * H_DIM);
  const float4* r1 = (const float4*)(ent + (size_t)p1 * H_DIM);
  const float4* r2 = (const float4*)(ent + (size_t)(CAP + p0) * H_DIM);
  const float4* r3 = (const float4*)(ent + (size_t)(CAP + p1) * H_DIM);
  float4 a = r0[threadIdx.x], b = r1[threadIdx.x];
  float4 c = r2[threadIdx.x], d = r3[threadIdx.x];
  float4 o = {a.x + b.x + c.x + d.x, a.y + b.y + c.y + d.y,
              a.z + b.z + c.z + d.z, a.w + b.w + c.w + d.w};
  ((float4*)(out + (size_t)t * H_DIM))[threadIdx.x] = o;
}

extern "C" void kernel_launch(void* const* d_in, const int* in_sizes, int n_in,
                              void* d_out, int out_size, void* d_ws, size_t ws_size,
                              hipStream_t stream) {
  const float* x    = (const float*)d_in[0];
  const int*   idx  = (const int*)d_in[1];
  const float* wts  = (const float*)d_in[2];
  const float* gate = (const float*)d_in[3];
  const float* up   = (const float*)d_in[4];
  const float* down = (const float*)d_in[5];
  float* out = (float*)d_out;
  char* ws = (char*)d_ws;

  unsigned short* bfs = (unsigned short*)(ws + 0);
  unsigned short* xb  = (unsigned short*)(ws + 0);            //  8,388,608
  unsigned short* gbw = (unsigned short*)(ws + 8388608);      // 33,554,432
  unsigned short* ubw = (unsigned short*)(ws + 41943040);     // 33,554,432
  unsigned short* dbw = (unsigned short*)(ws + 75497472);     // 33,554,432
  float*          ent = (float*)(ws + 0);                     // 75,497,472 (aliases xb|gbw|ubw)
  unsigned short* act = (unsigned short*)(ws + 109051904);    // 37,748,736
  int*   perm   = (int*)(ws + 146800640);
  float* pw     = (float*)(ws + 146837504);
  int*   inv    = (int*)(ws + 146874368);
  int*   counts = (int*)(ws + 146907136);
  int*   poff   = (int*)(ws + 146907200);

  route_kernel<<<1, 256, 0, stream>>>(idx, wts, perm, pw, inv, counts, poff);

  cast_all_kernel<<<DE / 2048, 256, 0, stream>>>(x, gate, up, down, bfs);

  gemm1_kernel<<<dim3(I_DIM / 64, 32, N_EXP), 512, 0, stream>>>(
      xb, gbw, ubw, perm, counts, poff, act);

  gemm2_kernel<<<dim3(16, 32, N_EXP), 512, 0, stream>>>(
      act, dbw, pw, counts, poff, ent);

  combine_kernel<<<N_TOK, 256, 0, stream>>>(ent, inv, out);
}

// Round 6
// 416.269 us; speedup vs baseline: 1.3338x; 1.0268x over previous
//
#include <hip/hip_runtime.h>

// MoE MLP: B=2,S=2048,H=1024,I=2048,E=8,TOPK=2  -> T=4096 tokens, 8192 entries.
// R6: fp32->bf16 cast FUSED into GEMM B-staging (global->VGPR->cvt->ds_write,
// software-pipelined prefetch). cast_all removed; only x gets a tiny cast.
// A-operands keep XOR-swizzled global_load_lds staging (R5).

#define H_DIM 1024
#define I_DIM 2048
#define N_EXP 8
#define N_TOK 4096
#define N_ENT 8192
#define CAP   9216   // 8192 + 8*128 padding capacity (segments padded to 128)

typedef __attribute__((ext_vector_type(8))) short bhalf8;
typedef __attribute__((ext_vector_type(4))) float floatx4;

__device__ __forceinline__ unsigned short f2bf(float f) {
  unsigned int u = __float_as_uint(f);
  u += 0x7fffu + ((u >> 16) & 1u);   // RNE
  return (unsigned short)(u >> 16);
}

// pack two fp32 -> bf16x2 (round-half-up), one v_perm_b32
__device__ __forceinline__ unsigned int pkbf(float a, float b) {
  unsigned int ua = __float_as_uint(a) + 0x8000u;
  unsigned int ub = __float_as_uint(b) + 0x8000u;
  return __builtin_amdgcn_perm(ub, ua, 0x07060302u);  // low16=a_hi, high16=b_hi
}

__device__ __forceinline__ void ld16(const void* g, void* l) {
  __builtin_amdgcn_global_load_lds(
      (const __attribute__((address_space(1))) unsigned int*)g,
      (__attribute__((address_space(3))) unsigned int*)l, 16, 0, 0);
}

// ---------------- routing ----------------
__global__ __launch_bounds__(256) void route_kernel(
    const int* __restrict__ idx, const float* __restrict__ wts,
    int* __restrict__ perm, float* __restrict__ pw, int* __restrict__ inv,
    int* __restrict__ counts, int* __restrict__ poff)
{
  __shared__ int cnt[N_EXP], cur[N_EXP], off[N_EXP];
  const int t = threadIdx.x;
  if (t < N_EXP) { cnt[t] = 0; cur[t] = 0; }
  __syncthreads();
  for (int i = t; i < N_ENT; i += 256) atomicAdd(&cnt[idx[i] & 7], 1);
  __syncthreads();
  if (t == 0) {
    int o = 0;
    for (int e = 0; e < N_EXP; e++) {
      off[e] = o; counts[e] = cnt[e]; poff[e] = o;
      o += ((cnt[e] + 127) >> 7) << 7;
    }
  }
  __syncthreads();
  for (int i = t; i < N_ENT; i += 256) {
    int e = idx[i] & 7;
    int p = atomicAdd(&cur[e], 1);
    int pos = off[e] + p;
    perm[pos] = i >> 1;
    pw[pos] = wts[i];
    inv[i] = pos;
  }
}

// ---------------- x cast fp32 -> bf16 (25 MB of traffic, ~5us) ----------------
__global__ __launch_bounds__(256) void cast_x_kernel(
    const float* __restrict__ s, unsigned short* __restrict__ d)
{
  int i = (blockIdx.x * 256 + threadIdx.x) * 8;
  const float4* sp = (const float4*)(s + i);
  float4 a = sp[0], b = sp[1];
  bhalf8 o;
  o[0] = (short)f2bf(a.x); o[1] = (short)f2bf(a.y); o[2] = (short)f2bf(a.z); o[3] = (short)f2bf(a.w);
  o[4] = (short)f2bf(b.x); o[5] = (short)f2bf(b.y); o[6] = (short)f2bf(b.z); o[7] = (short)f2bf(b.w);
  *(bhalf8*)(d + i) = o;
}

// ---------------- GEMM1: act = silu(X Wg^T) * (X Wu^T) ----------------
// 512 threads, block tile 256(M) x 64(N) x 2 matrices, BK=64.
// A: swizzled global_load_lds from xb (bf16). B: fp32 gate/up -> VGPR prefetch
// -> pkbf -> ds_write_b128 into K-chunked LDS (cell (c,n) at (c*64+n)*16B).
__global__ __launch_bounds__(512, 4) void gemm1_kernel(
    const unsigned short* __restrict__ xb,
    const float* __restrict__ gw,
    const float* __restrict__ uw,
    const int* __restrict__ perm,
    const int* __restrict__ counts,
    const int* __restrict__ poff,
    unsigned short* __restrict__ act)
{
  const int e = blockIdx.z;
  const int Ne = counts[e];
  const int mt = blockIdx.y;
  if (mt * 256 >= Ne) return;
  const int NeR = ((Ne + 127) >> 7) << 7;
  const int base = poff[e];
  const int n0 = blockIdx.x * 64;

  __shared__ __align__(16) unsigned short As[256 * 64];   // 32 KB (swizzled)
  __shared__ __align__(16) unsigned short Bgs[64 * 64];   //  8 KB (K-chunked)
  __shared__ __align__(16) unsigned short Bus[64 * 64];   //  8 KB (K-chunked)

  const int tid = threadIdx.x;
  const int lane = tid & 63;
  const int w = tid >> 6;          // 0..7
  const int wmi = w >> 1;          // 0..3 (M)
  const int wnj = w & 1;           // 0..1 (N)
  const int i3 = lane >> 3, i7 = lane & 7;
  const int swc = (i7 ^ i3) * 8;   // A swizzle chunk offset

  // A: 4 ld16/wave -> 32 rows
  const unsigned short* pA[4]; unsigned short* lA[4];
#pragma unroll
  for (int t = 0; t < 4; t++) {
    int rloc = w * 32 + t * 8 + i3;
    int rr = mt * 256 + rloc; rr = rr < Ne ? rr : Ne - 1;
    pA[t] = xb + (size_t)perm[base + rr] * H_DIM + swc;
    lA[t] = &As[(w * 32 + t * 8) * 64];
  }
  // B: 1 cell per thread per matrix: row nloc, chunk i7 (8 fp32 = 2 float4)
  const int nlocB = w * 8 + i3;
  const size_t wb = (size_t)e * (I_DIM * H_DIM) + (size_t)(n0 + nlocB) * H_DIM + i7 * 8;
  const float* pg = gw + wb;
  const float* pu = uw + wb;
  unsigned short* lBg = &Bgs[(i7 * 64 + nlocB) * 8];
  unsigned short* lBu = &Bus[(i7 * 64 + nlocB) * 8];

  floatx4 zero = {0.f, 0.f, 0.f, 0.f};
  floatx4 accg[4][2], accu[4][2];
#pragma unroll
  for (int i = 0; i < 4; i++)
#pragma unroll
    for (int j = 0; j < 2; j++) { accg[i][j] = zero; accu[i][j] = zero; }

  const int quad = lane >> 4, lm = lane & 15;
  const int s7 = lm & 7;

  // prefetch B for k0=0
  float4 g0 = *(const float4*)(pg);
  float4 g1 = *(const float4*)(pg + 4);
  float4 u0 = *(const float4*)(pu);
  float4 u1 = *(const float4*)(pu + 4);

  for (int k0 = 0; k0 < H_DIM; k0 += 64) {
    __syncthreads();
#pragma unroll
    for (int t = 0; t < 4; t++) ld16(pA[t] + k0, lA[t]);
    *(uint4*)lBg = make_uint4(pkbf(g0.x, g0.y), pkbf(g0.z, g0.w),
                              pkbf(g1.x, g1.y), pkbf(g1.z, g1.w));
    *(uint4*)lBu = make_uint4(pkbf(u0.x, u0.y), pkbf(u0.z, u0.w),
                              pkbf(u1.x, u1.y), pkbf(u1.z, u1.w));
    __syncthreads();
    if (k0 + 64 < H_DIM) {   // prefetch next B tile; overlaps with MFMA below
      g0 = *(const float4*)(pg + k0 + 64);
      g1 = *(const float4*)(pg + k0 + 68);
      u0 = *(const float4*)(pu + k0 + 64);
      u1 = *(const float4*)(pu + k0 + 68);
    }
#pragma unroll
    for (int kk = 0; kk < 2; kk++) {
      const int kq = kk * 4 + quad;
      const int ko = (kq ^ s7) * 8;
      bhalf8 a[4], bg[2], bu[2];
#pragma unroll
      for (int i = 0; i < 4; i++)
        a[i] = *(const bhalf8*)&As[(wmi * 64 + i * 16 + lm) * 64 + ko];
#pragma unroll
      for (int j = 0; j < 2; j++) {
        bg[j] = *(const bhalf8*)&Bgs[(kq * 64 + wnj * 32 + j * 16 + lm) * 8];
        bu[j] = *(const bhalf8*)&Bus[(kq * 64 + wnj * 32 + j * 16 + lm) * 8];
      }
#pragma unroll
      for (int i = 0; i < 4; i++)
#pragma unroll
        for (int j = 0; j < 2; j++) {
          accg[i][j] = __builtin_amdgcn_mfma_f32_16x16x32_bf16(a[i], bg[j], accg[i][j], 0, 0, 0);
          accu[i][j] = __builtin_amdgcn_mfma_f32_16x16x32_bf16(a[i], bu[j], accu[i][j], 0, 0, 0);
        }
    }
  }

#pragma unroll
  for (int i = 0; i < 4; i++) {
#pragma unroll
    for (int r = 0; r < 4; r++) {
      int row = mt * 256 + wmi * 64 + i * 16 + quad * 4 + r;
      if (row < NeR) {
        size_t rowoff = (size_t)(base + row) * I_DIM;
#pragma unroll
        for (int j = 0; j < 2; j++) {
          int col = n0 + wnj * 32 + j * 16 + lm;
          float g = accg[i][j][r];
          float u = accu[i][j][r];
          float h = (g / (1.f + __expf(-g))) * u;
          act[rowoff + col] = (unsigned short)f2bf(h);
        }
      }
    }
  }
}

// ---------------- GEMM2: ent[half][row] = pw[row]*(act x down^T over K-half) ----------------
// 512 threads, block tile 256x128, BK=64, split-K=2: blockIdx.x = (kh<<3)|nx.
// A: swizzled ld16 from act (bf16). B: fp32 down -> VGPR prefetch -> ds_write.
__global__ __launch_bounds__(512, 4) void gemm2_kernel(
    const unsigned short* __restrict__ act,
    const float* __restrict__ dw,
    const float* __restrict__ pw,
    const int* __restrict__ counts,
    const int* __restrict__ poff,
    float* __restrict__ ent)
{
  const int e = blockIdx.z;
  const int Ne = counts[e];
  const int mt = blockIdx.y;
  if (mt * 256 >= Ne) return;
  const int NeR = ((Ne + 127) >> 7) << 7;
  const int base = poff[e];
  const int n0 = (blockIdx.x & 7) * 128;
  const int k_lo = (blockIdx.x >> 3) * (I_DIM / 2);

  __shared__ __align__(16) unsigned short As[256 * 64];   // 32 KB (swizzled)
  __shared__ __align__(16) unsigned short Bs[128 * 64];   // 16 KB (K-chunked)

  const int tid = threadIdx.x;
  const int lane = tid & 63;
  const int w = tid >> 6;
  const int wmi = w >> 1, wnj = w & 1;
  const int i3 = lane >> 3, i7 = lane & 7;
  const int swc = (i7 ^ i3) * 8;

  const unsigned short* pA[4]; unsigned short* lA[4];
#pragma unroll
  for (int t = 0; t < 4; t++) {
    int rloc = w * 32 + t * 8 + i3;
    int rr = mt * 256 + rloc; rr = rr < NeR ? rr : NeR - 1;
    pA[t] = act + (size_t)(base + rr) * I_DIM + k_lo + swc;
    lA[t] = &As[(w * 32 + t * 8) * 64];
  }
  // B: 2 cells/thread: rows w*16+{0,8}+i3, chunk i7
  const float* pB[2]; unsigned short* lB[2];
#pragma unroll
  for (int t = 0; t < 2; t++) {
    int rloc = w * 16 + t * 8 + i3;
    pB[t] = dw + (size_t)e * (H_DIM * I_DIM) + (size_t)(n0 + rloc) * I_DIM + k_lo + i7 * 8;
    lB[t] = &Bs[(i7 * 128 + rloc) * 8];
  }

  floatx4 zero = {0.f, 0.f, 0.f, 0.f};
  floatx4 acc[4][4];
#pragma unroll
  for (int i = 0; i < 4; i++)
#pragma unroll
    for (int j = 0; j < 4; j++) acc[i][j] = zero;

  const int quad = lane >> 4, lm = lane & 15;
  const int s7 = lm & 7;

  float4 b00 = *(const float4*)(pB[0]);
  float4 b01 = *(const float4*)(pB[0] + 4);
  float4 b10 = *(const float4*)(pB[1]);
  float4 b11 = *(const float4*)(pB[1] + 4);

  for (int k0 = 0; k0 < I_DIM / 2; k0 += 64) {
    __syncthreads();
#pragma unroll
    for (int t = 0; t < 4; t++) ld16(pA[t] + k0, lA[t]);
    *(uint4*)lB[0] = make_uint4(pkbf(b00.x, b00.y), pkbf(b00.z, b00.w),
                                pkbf(b01.x, b01.y), pkbf(b01.z, b01.w));
    *(uint4*)lB[1] = make_uint4(pkbf(b10.x, b10.y), pkbf(b10.z, b10.w),
                                pkbf(b11.x, b11.y), pkbf(b11.z, b11.w));
    __syncthreads();
    if (k0 + 64 < I_DIM / 2) {
      b00 = *(const float4*)(pB[0] + k0 + 64);
      b01 = *(const float4*)(pB[0] + k0 + 68);
      b10 = *(const float4*)(pB[1] + k0 + 64);
      b11 = *(const float4*)(pB[1] + k0 + 68);
    }
#pragma unroll
    for (int kk = 0; kk < 2; kk++) {
      const int kq = kk * 4 + quad;
      const int ko = (kq ^ s7) * 8;
      bhalf8 a[4], b[4];
#pragma unroll
      for (int i = 0; i < 4; i++)
        a[i] = *(const bhalf8*)&As[(wmi * 64 + i * 16 + lm) * 64 + ko];
#pragma unroll
      for (int j = 0; j < 4; j++)
        b[j] = *(const bhalf8*)&Bs[(kq * 128 + wnj * 64 + j * 16 + lm) * 8];
#pragma unroll
      for (int i = 0; i < 4; i++)
#pragma unroll
        for (int j = 0; j < 4; j++)
          acc[i][j] = __builtin_amdgcn_mfma_f32_16x16x32_bf16(a[i], b[j], acc[i][j], 0, 0, 0);
    }
  }

  float* enth = ent + (size_t)(blockIdx.x >> 3) * CAP * H_DIM;
#pragma unroll
  for (int i = 0; i < 4; i++) {
#pragma unroll
    for (int r = 0; r < 4; r++) {
      int row = mt * 256 + wmi * 64 + i * 16 + quad * 4 + r;
      if (row < Ne) {
        float wt = pw[base + row];
        float* orow = enth + (size_t)(base + row) * H_DIM;
#pragma unroll
        for (int j = 0; j < 4; j++) {
          int col = n0 + wnj * 64 + j * 16 + lm;
          orow[col] = wt * acc[i][j][r];
        }
      }
    }
  }
}

// ---------------- combine ----------------
__global__ __launch_bounds__(256) void combine_kernel(
    const float* __restrict__ ent, const int* __restrict__ inv,
    float* __restrict__ out)
{
  const int t = blockIdx.x;
  const int p0 = inv[2 * t], p1 = inv[2 * t + 1];
  const float4* r0 = (const float4*)(ent + (size_t)p0 * H_DIM);
  const float4* r1 = (const float4*)(ent + (size_t)p1 * H_DIM);
  const float4* r2 = (const float4*)(ent + (size_t)(CAP + p0) * H_DIM);
  const float4* r3 = (const float4*)(ent + (size_t)(CAP + p1) * H_DIM);
  float4 a = r0[threadIdx.x], b = r1[threadIdx.x];
  float4 c = r2[threadIdx.x], d = r3[threadIdx.x];
  float4 o = {a.x + b.x + c.x + d.x, a.y + b.y + c.y + d.y,
              a.z + b.z + c.z + d.z, a.w + b.w + c.w + d.w};
  ((float4*)(out + (size_t)t * H_DIM))[threadIdx.x] = o;
}

extern "C" void kernel_launch(void* const* d_in, const int* in_sizes, int n_in,
                              void* d_out, int out_size, void* d_ws, size_t ws_size,
                              hipStream_t stream) {
  const float* x    = (const float*)d_in[0];
  const int*   idx  = (const int*)d_in[1];
  const float* wts  = (const float*)d_in[2];
  const float* gate = (const float*)d_in[3];
  const float* up   = (const float*)d_in[4];
  const float* down = (const float*)d_in[5];
  float* out = (float*)d_out;
  char* ws = (char*)d_ws;

  // workspace layout (bytes)
  float*          ent = (float*)(ws + 0);                   // 75,497,472 (2*CAP*H*4)
  unsigned short* act = (unsigned short*)(ws + 75497472);   // 37,748,736 (CAP*I*2)
  unsigned short* xb  = (unsigned short*)(ws + 113246208);  //  8,388,608
  int*   perm   = (int*)(ws + 121634816);                   // 36,864
  float* pw     = (float*)(ws + 121671680);                 // 36,864
  int*   inv    = (int*)(ws + 121708544);                   // 32,768
  int*   counts = (int*)(ws + 121741312);                   // 32
  int*   poff   = (int*)(ws + 121741376);                   // 32

  route_kernel<<<1, 256, 0, stream>>>(idx, wts, perm, pw, inv, counts, poff);

  cast_x_kernel<<<(N_TOK * H_DIM) / (256 * 8), 256, 0, stream>>>(x, xb);

  gemm1_kernel<<<dim3(I_DIM / 64, 32, N_EXP), 512, 0, stream>>>(
      xb, gate, up, perm, counts, poff, act);

  gemm2_kernel<<<dim3(16, 32, N_EXP), 512, 0, stream>>>(
      act, down, pw, counts, poff, ent);

  combine_kernel<<<N_TOK, 256, 0, stream>>>(ent, inv, out);
}